// Round 14
// baseline (1859.139 us; speedup 1.0000x reference)
//
#include <hip/hip_runtime.h>

#define NPTS 256
#define NBATCH 64
#define BIGF 1e30f
#define KBIG 0x7149F200u   // __float_as_uint(1e30f) & 0xFFFFFF00

__device__ __forceinline__ float rlane(float v, int l) {
    return __uint_as_float((unsigned int)__builtin_amdgcn_readlane((int)__float_as_uint(v), l));
}
__device__ __forceinline__ int rlanei(int v, int l) {
    return __builtin_amdgcn_readlane(v, l);
}
__device__ __forceinline__ float rawsqrt(float x) {
    return __builtin_amdgcn_sqrtf(x);
}

// Uniform-slot select (slot wave-uniform); cold paths only.
#define SEL4(a, s) ((s) == 0 ? a[0] : (s) == 1 ? a[1] : (s) == 2 ? a[2] : a[3])

#define DPP_UMIN(v, ctrl) \
    (min)((v), (unsigned int)__builtin_amdgcn_update_dpp( \
        (int)(v), (int)(v), (ctrl), 0xf, 0xf, false))
#define DPP_FMIN(v, ctrl) \
    fminf(v, __int_as_float(__builtin_amdgcn_update_dpp( \
        __float_as_int(v), __float_as_int(v), (ctrl), 0xf, 0xf, false)))

// Full-wave exact fmin; uniform result via lane-63 readlane. (R3/R5-proven.)
__device__ __forceinline__ float wave_fmin_bcast(float v) {
    v = DPP_FMIN(v, 0x111);   // row_shr:1
    v = DPP_FMIN(v, 0x112);   // row_shr:2
    v = DPP_FMIN(v, 0x114);   // row_shr:4
    v = DPP_FMIN(v, 0x118);   // row_shr:8
    v = DPP_FMIN(v, 0x142);   // row_bcast:15
    v = DPP_FMIN(v, 0x143);   // row_bcast:31
    return rlane(v, 63);
}

__global__ void zero_out_kernel(float* out, int n) {
    int i = blockIdx.x * blockDim.x + threadIdx.x;
    if (i < n) out[i] = 0.0f;
}

// One expansion step of the delta-accumulated Dijkstra (R10 dataflow).
#define EXPAND_ONCE                                                              \
    {                                                                            \
        _Pragma("unroll")                                                        \
        for (int c = 0; c < 4; ++c) {                                            \
            float dx = bx - tx[c], dy = by - ty[c], dz = bz - tz[c];             \
            float d = rawsqrt(dx * dx + dy * dy + dz * dz);                      \
            float cand = d + w[c];              /* == d - ukey - vv[c] */        \
            unsigned int kc = (__float_as_uint(cand) & 0xFFFFFF00u) | colu[c];   \
            if (kc < kMv[c]) { kMv[c] = kc; way[c] = j0; }                       \
        }                                                                        \
        unsigned int vr = (min)((min)(kMv[0], kMv[1]), (min)(kMv[2], kMv[3]));   \
        vr = DPP_UMIN(vr, 0x111);   /* row_shr:1 */                              \
        vr = DPP_UMIN(vr, 0x112);   /* row_shr:2 */                              \
        vr = DPP_UMIN(vr, 0x114);   /* row_shr:4 */                              \
        const unsigned int q0 = (unsigned int)rlanei((int)vr, 7);                \
        const unsigned int q1 = (unsigned int)rlanei((int)vr, 15);               \
        const unsigned int q2 = (unsigned int)rlanei((int)vr, 23);               \
        const unsigned int q3 = (unsigned int)rlanei((int)vr, 31);               \
        const unsigned int q4 = (unsigned int)rlanei((int)vr, 39);               \
        const unsigned int q5 = (unsigned int)rlanei((int)vr, 47);               \
        const unsigned int q6 = (unsigned int)rlanei((int)vr, 55);               \
        const unsigned int q7 = (unsigned int)rlanei((int)vr, 63);               \
        const unsigned int kk = (min)((min)((min)(q0, q1), (min)(q2, q3)),       \
                                      (min)((min)(q4, q5), (min)(q6, q7)));      \
        const int   j1   = (int)(kk & 0xFFu);                                    \
        const float gmin = __uint_as_float(kk & 0xFFFFFF00u);                    \
        const int osl = j1 >> 6, oln = j1 & 63;                                  \
        float uj, nbx, nby, nbz;                                                 \
        switch (osl) {                                                           \
            case 0:  uj = rlane(upc[0], oln); nbx = rlane(rxc[0], oln); nby = rlane(ryc[0], oln); nbz = rlane(rzc[0], oln); break; \
            case 1:  uj = rlane(upc[1], oln); nbx = rlane(rxc[1], oln); nby = rlane(ryc[1], oln); nbz = rlane(rzc[1], oln); break; \
            case 2:  uj = rlane(upc[2], oln); nbx = rlane(rxc[2], oln); nby = rlane(ryc[2], oln); nbz = rlane(rzc[2], oln); break; \
            default: uj = rlane(upc[3], oln); nbx = rlane(rxc[3], oln); nby = rlane(ryc[3], oln); nbz = rlane(rzc[3], oln); break; \
        }                                                                        \
        const unsigned long long fm =                                            \
            (osl == 0 ? freem[0] : osl == 1 ? freem[1] : osl == 2 ? freem[2] : freem[3]); \
        if ((fm >> oln) & 1ull) { jfin = j1; D = gmin; break; }                  \
        _Pragma("unroll")                                                        \
        for (int c = 0; c < 4; ++c)                                              \
            if (c == osl && lane == oln) {                                       \
                usedm |= (1 << c);                                               \
                Tv[c] = gmin;                                                    \
                vsave[c] = vv[c];                                                \
                vv[c] = -BIGF;                 /* -> w = +BIGF -> excluded */    \
                kMv[c] = KBIG | colu[c];       /* frozen */                      \
            }                                                                    \
        const float gu = gmin - uj;                                              \
        _Pragma("unroll")                                                        \
        for (int c = 0; c < 4; ++c) w[c] = gu - vv[c];                           \
        bx = nbx; by = nby; bz = nbz;                                            \
        j0 = j1;                                                                 \
    }

// One wave per batch; lane owns columns/rows {lane, 64+lane, 128+lane, 192+lane}.
// JV: column reduction -> greedy claim -> free-argmin row pass (R14: match
// unmatched rows whose exact reduced-cost argmin lands on a FREE column;
// u[i]=mu1, v untouched -> exact feasibility + CS, cannot grow other trees)
// -> delta-accumulated Dijkstra searches (R13 hot body).
__launch_bounds__(64, 1)
__global__ void hungarian_wave(const float* __restrict__ pred,
                               const float* __restrict__ target,
                               float* __restrict__ out) {
    const int b    = blockIdx.x;
    const int lane = threadIdx.x;

    const float* pb = pred   + (size_t)b * NPTS * 3;
    const float* tb = target + (size_t)b * NPTS * 3;

    float prx[4], pry[4], prz[4];      // pred (row) points, row = c*64+lane
    float tx[4], ty[4], tz[4];         // target (col) points, col = c*64+lane
    float vv[4], upc[4], Tv[4], w[4], vsave[4];
    float rxc[4], ryc[4], rzc[4];      // matched-row coords, column-attached
    unsigned int kMv[4];               // packed slack keys: (bits(M)&~0xFF)|col
    int   pc[4]  = {-1, -1, -1, -1};   // matched row per column (-1 = free)
    int   way[4];
    unsigned int colu[4];              // this lane's column ids
    unsigned long long freem[4];       // free-COLUMN masks (wave-uniform)

#pragma unroll
    for (int c = 0; c < 4; ++c) {
        int idx = c * 64 + lane;
        prx[c] = pb[idx * 3 + 0]; pry[c] = pb[idx * 3 + 1]; prz[c] = pb[idx * 3 + 2];
        tx[c]  = tb[idx * 3 + 0]; ty[c]  = tb[idx * 3 + 1]; tz[c]  = tb[idx * 3 + 2];
        upc[c] = 0.f; Tv[c] = 0.f; vsave[c] = 0.f;
        rxc[c] = 0.f; ryc[c] = 0.f; rzc[c] = 0.f;
        colu[c] = (unsigned int)idx;
        freem[c] = ~0ull;
    }

    // ---- Phase 1a: column reduction. vv[c] = min_r d(r, col), colrow = argmin ----
    float colmin[4] = {BIGF, BIGF, BIGF, BIGF};
    int   colrow[4] = {0, 0, 0, 0};
#pragma unroll
    for (int rs = 0; rs < 4; ++rs) {
        for (int rl = 0; rl < 64; ++rl) {
            float bx = rlane(prx[rs], rl), by = rlane(pry[rs], rl), bz = rlane(prz[rs], rl);
            int r = rs * 64 + rl;
#pragma unroll
            for (int c = 0; c < 4; ++c) {
                float dx = bx - tx[c], dy = by - ty[c], dz = bz - tz[c];
                float d = rawsqrt(dx * dx + dy * dy + dz * dz);
                if (d < colmin[c]) { colmin[c] = d; colrow[c] = r; }
            }
        }
    }
#pragma unroll
    for (int c = 0; c < 4; ++c) vv[c] = colmin[c];

    // ---- Phase 1b: greedy claim — column (ascending) claims its argmin row if free ----
    unsigned long long frm[4];         // free-row masks (wave-uniform values)
    frm[0] = frm[1] = frm[2] = frm[3] = ~0ull;
#pragma unroll
    for (int cs = 0; cs < 4; ++cs) {
        for (int l = 0; l < 64; ++l) {
            int r = rlanei(colrow[cs], l);
            int rs = r >> 6, rl2 = r & 63;
            unsigned long long bit = 1ull << rl2;
            bool free_row = (SEL4(frm, rs) & bit) != 0ull;
            if (free_row) {
#pragma unroll
                for (int s = 0; s < 4; ++s)
                    if (s == rs) frm[s] &= ~bit;
                float bx, by, bz;
                switch (rs) {
                    case 0:  bx = rlane(prx[0], rl2); by = rlane(pry[0], rl2); bz = rlane(prz[0], rl2); break;
                    case 1:  bx = rlane(prx[1], rl2); by = rlane(pry[1], rl2); bz = rlane(prz[1], rl2); break;
                    case 2:  bx = rlane(prx[2], rl2); by = rlane(pry[2], rl2); bz = rlane(prz[2], rl2); break;
                    default: bx = rlane(prx[3], rl2); by = rlane(pry[3], rl2); bz = rlane(prz[3], rl2); break;
                }
                if (lane == l) {
                    pc[cs] = r; upc[cs] = 0.f;
                    rxc[cs] = bx; ryc[cs] = by; rzc[cs] = bz;
                }
#pragma unroll
                for (int s = 0; s < 4; ++s)
                    if (s == cs) freem[s] &= ~(1ull << l);   // column cs*64+l matched
            }
        }
    }

    // ---- Phase 1c: free-argmin row pass (exact; v untouched) ----
    // For each unmatched row i: mu1 = exact min_j (d(i,j) - v[j]), j* = exact
    // argmin (first-index ties). If j* free: match (i,j*), u[i] = mu1 -> all
    // row slacks >= 0 exactly, matched slack == 0 exactly. Deletes the row's
    // entire Dijkstra search at the cost of one cold reduce step.
#pragma unroll
    for (int is = 0; is < 4; ++is) {
        unsigned long long scan = frm[is];
        while (scan) {
            const int il = (int)__builtin_ctzll(scan);
            scan &= (scan - 1);
            const int i = is * 64 + il;

            float bx, by, bz;
            switch (is) {
                case 0:  bx = rlane(prx[0], il); by = rlane(pry[0], il); bz = rlane(prz[0], il); break;
                case 1:  bx = rlane(prx[1], il); by = rlane(pry[1], il); bz = rlane(prz[1], il); break;
                case 2:  bx = rlane(prx[2], il); by = rlane(pry[2], il); bz = rlane(prz[2], il); break;
                default: bx = rlane(prx[3], il); by = rlane(pry[3], il); bz = rlane(prz[3], il); break;
            }

            float lval = BIGF; int lcol = 0;
#pragma unroll
            for (int c = 0; c < 4; ++c) {
                float dx = bx - tx[c], dy = by - ty[c], dz = bz - tz[c];
                float r = rawsqrt(dx * dx + dy * dy + dz * dz) - vv[c];
                if (r < lval) { lval = r; lcol = (int)colu[c]; }
            }
            const float mu1 = wave_fmin_bcast(lval);
            const unsigned long long msk = __ballot(lval == mu1);
            const int fl = (int)__builtin_ctzll(msk);
            const int j1 = rlanei(lcol, fl);
            const int osl = j1 >> 6, oln = j1 & 63;

            const unsigned long long fm = SEL4(freem, osl);
            if ((fm >> oln) & 1ull) {           // argmin column is free: claim it
#pragma unroll
                for (int s = 0; s < 4; ++s) {
                    if (s == osl) freem[s] &= ~(1ull << oln);
                    if (s == is)  frm[s]   &= ~(1ull << il);
                }
#pragma unroll
                for (int c = 0; c < 4; ++c)
                    if (c == osl && lane == oln) {
                        pc[c] = i; upc[c] = mu1;
                        rxc[c] = bx; ryc[c] = by; rzc[c] = bz;
                    }
            }
        }
    }

    // ---- Phase 2: Dijkstra shortest-path for remaining free rows ----
#pragma unroll
    for (int is = 0; is < 4; ++is) {
        unsigned long long m = frm[is];
        while (m) {
            const int il = (int)__builtin_ctzll(m);
            m &= (m - 1);
            const int i = is * 64 + il;

            float rootx, rooty, rootz;
            switch (is) {
                case 0:  rootx = rlane(prx[0], il); rooty = rlane(pry[0], il); rootz = rlane(prz[0], il); break;
                case 1:  rootx = rlane(prx[1], il); rooty = rlane(pry[1], il); rootz = rlane(prz[1], il); break;
                case 2:  rootx = rlane(prx[2], il); rooty = rlane(pry[2], il); rootz = rlane(prz[2], il); break;
                default: rootx = rlane(prx[3], il); rooty = rlane(pry[3], il); rootz = rlane(prz[3], il); break;
            }

#pragma unroll
            for (int c = 0; c < 4; ++c) {
                kMv[c] = KBIG | colu[c];
                w[c]   = -vv[c];
            }
            int usedm = 0;

            float bx = rootx, by = rooty, bz = rootz;
            int j0 = -1;
            int jfin = 0;
            float D = 0.f;

            while (true) {
                EXPAND_ONCE
                EXPAND_ONCE
            }

            // Commit duals for tree columns: net amount = D_final - D_at_use
#pragma unroll
            for (int c = 0; c < 4; ++c)
                if ((usedm >> c) & 1) {
                    vv[c] = vsave[c] + Tv[c] - D;
                    upc[c] += D - Tv[c];
                }

            // Newly matched column leaves the free set
            {
                const int wsl = jfin >> 6;
                const unsigned long long bit = 1ull << (jfin & 63);
#pragma unroll
                for (int s = 0; s < 4; ++s)
                    if (s == wsl) freem[s] &= ~bit;
            }

            // Augment along alternating path (cold)
            int jc = jfin;
            while (true) {
                const int osl = jc >> 6, oln = jc & 63;
                int jw;
                switch (osl) {
                    case 0:  jw = rlanei(way[0], oln); break;
                    case 1:  jw = rlanei(way[1], oln); break;
                    case 2:  jw = rlanei(way[2], oln); break;
                    default: jw = rlanei(way[3], oln); break;
                }
                int np_; float nup, nrx, nry, nrz;
                if (jw < 0) {
                    np_ = i; nup = D; nrx = rootx; nry = rooty; nrz = rootz;
                } else {
                    const int wsl = jw >> 6, wln = jw & 63;
                    switch (wsl) {
                        case 0:  np_ = rlanei(pc[0], wln); nup = rlane(upc[0], wln); nrx = rlane(rxc[0], wln); nry = rlane(ryc[0], wln); nrz = rlane(rzc[0], wln); break;
                        case 1:  np_ = rlanei(pc[1], wln); nup = rlane(upc[1], wln); nrx = rlane(rxc[1], wln); nry = rlane(ryc[1], wln); nrz = rlane(rzc[1], wln); break;
                        case 2:  np_ = rlanei(pc[2], wln); nup = rlane(upc[2], wln); nrx = rlane(rxc[2], wln); nry = rlane(ryc[2], wln); nrz = rlane(rzc[2], wln); break;
                        default: np_ = rlanei(pc[3], wln); nup = rlane(upc[3], wln); nrx = rlane(rxc[3], wln); nry = rlane(ryc[3], wln); nrz = rlane(rzc[3], wln); break;
                    }
                }
#pragma unroll
                for (int c = 0; c < 4; ++c)
                    if (c == osl && lane == oln) {
                        pc[c] = np_; upc[c] = nup;
                        rxc[c] = nrx; ryc[c] = nry; rzc[c] = nrz;
                    }
                if (jw < 0) break;
                jc = jw;
            }
        }
    }

    // ---- Matched cost (coords column-attached; IEEE sqrt for final accuracy) ----
    float s = 0.f;
#pragma unroll
    for (int c = 0; c < 4; ++c) {
        float dx = rxc[c] - tx[c], dy = ryc[c] - ty[c], dz = rzc[c] - tz[c];
        s += sqrtf(dx * dx + dy * dy + dz * dz);
    }
#pragma unroll
    for (int off = 1; off < 64; off <<= 1) s += __shfl_xor(s, off, 64);
    if (lane == 0) atomicAdd(out, s / (float)NBATCH);
}

extern "C" void kernel_launch(void* const* d_in, const int* in_sizes, int n_in,
                              void* d_out, int out_size, void* d_ws, size_t ws_size,
                              hipStream_t stream) {
    const float* pred   = (const float*)d_in[0];
    const float* target = (const float*)d_in[1];
    float* out = (float*)d_out;

    zero_out_kernel<<<1, 64, 0, stream>>>(out, out_size);
    hungarian_wave<<<NBATCH, 64, 0, stream>>>(pred, target, out);
}

// Round 15
// 1831.766 us; speedup vs baseline: 1.0149x; 1.0149x over previous
//
#include <hip/hip_runtime.h>

#define NPTS 256
#define NBATCH 64
#define BIGF 1e30f
#define KBIG 0x7149F200u   // __float_as_uint(1e30f) & 0xFFFFFF00

__device__ __forceinline__ float rlane(float v, int l) {
    return __uint_as_float((unsigned int)__builtin_amdgcn_readlane((int)__float_as_uint(v), l));
}
__device__ __forceinline__ int rlanei(int v, int l) {
    return __builtin_amdgcn_readlane(v, l);
}
__device__ __forceinline__ float rawsqrt(float x) {
    return __builtin_amdgcn_sqrtf(x);
}

// Uniform-slot select (slot wave-uniform); cold paths only.
#define SEL4(a, s) ((s) == 0 ? a[0] : (s) == 1 ? a[1] : (s) == 2 ? a[2] : a[3])

#define DPP_UMIN(v, ctrl) \
    (min)((v), (unsigned int)__builtin_amdgcn_update_dpp( \
        (int)(v), (int)(v), (ctrl), 0xf, 0xf, false))

__global__ void zero_out_kernel(float* out, int n) {
    int i = blockIdx.x * blockDim.x + threadIdx.x;
    if (i < n) out[i] = 0.0f;
}

// One expansion step of the delta-accumulated Dijkstra (R10 dataflow).
// Reduce = 3 DPP row_shr (8-block minima in lanes 7,15,..,63) + 8 parallel
// readlanes + SALU min tree. `break` exits the enclosing while on augment.
#define EXPAND_ONCE                                                              \
    {                                                                            \
        _Pragma("unroll")                                                        \
        for (int c = 0; c < 4; ++c) {                                            \
            float dx = bx - tx[c], dy = by - ty[c], dz = bz - tz[c];             \
            float d = rawsqrt(dx * dx + dy * dy + dz * dz);                      \
            float cand = d + w[c];              /* == d - ukey - vv[c] */        \
            unsigned int kc = (__float_as_uint(cand) & 0xFFFFFF00u) | colu[c];   \
            if (kc < kMv[c]) { kMv[c] = kc; way[c] = j0; }                       \
        }                                                                        \
        unsigned int vr = (min)((min)(kMv[0], kMv[1]), (min)(kMv[2], kMv[3]));   \
        vr = DPP_UMIN(vr, 0x111);   /* row_shr:1 */                              \
        vr = DPP_UMIN(vr, 0x112);   /* row_shr:2 */                              \
        vr = DPP_UMIN(vr, 0x114);   /* row_shr:4 */                              \
        const unsigned int q0 = (unsigned int)rlanei((int)vr, 7);                \
        const unsigned int q1 = (unsigned int)rlanei((int)vr, 15);               \
        const unsigned int q2 = (unsigned int)rlanei((int)vr, 23);               \
        const unsigned int q3 = (unsigned int)rlanei((int)vr, 31);               \
        const unsigned int q4 = (unsigned int)rlanei((int)vr, 39);               \
        const unsigned int q5 = (unsigned int)rlanei((int)vr, 47);               \
        const unsigned int q6 = (unsigned int)rlanei((int)vr, 55);               \
        const unsigned int q7 = (unsigned int)rlanei((int)vr, 63);               \
        const unsigned int kk = (min)((min)((min)(q0, q1), (min)(q2, q3)),       \
                                      (min)((min)(q4, q5), (min)(q6, q7)));      \
        const int   j1   = (int)(kk & 0xFFu);                                    \
        const float gmin = __uint_as_float(kk & 0xFFFFFF00u);                    \
        const int osl = j1 >> 6, oln = j1 & 63;                                  \
        float uj, nbx, nby, nbz;                                                 \
        switch (osl) {                                                           \
            case 0:  uj = rlane(upc[0], oln); nbx = rlane(rxc[0], oln); nby = rlane(ryc[0], oln); nbz = rlane(rzc[0], oln); break; \
            case 1:  uj = rlane(upc[1], oln); nbx = rlane(rxc[1], oln); nby = rlane(ryc[1], oln); nbz = rlane(rzc[1], oln); break; \
            case 2:  uj = rlane(upc[2], oln); nbx = rlane(rxc[2], oln); nby = rlane(ryc[2], oln); nbz = rlane(rzc[2], oln); break; \
            default: uj = rlane(upc[3], oln); nbx = rlane(rxc[3], oln); nby = rlane(ryc[3], oln); nbz = rlane(rzc[3], oln); break; \
        }                                                                        \
        const unsigned long long fm =                                            \
            (osl == 0 ? freem[0] : osl == 1 ? freem[1] : osl == 2 ? freem[2] : freem[3]); \
        if ((fm >> oln) & 1ull) { jfin = j1; D = gmin; break; }                  \
        _Pragma("unroll")                                                        \
        for (int c = 0; c < 4; ++c)                                              \
            if (c == osl && lane == oln) {                                       \
                usedm |= (1 << c);                                               \
                Tv[c] = gmin;                                                    \
                vsave[c] = vv[c];                                                \
                vv[c] = -BIGF;                 /* -> w = +BIGF -> excluded */    \
                kMv[c] = KBIG | colu[c];       /* frozen */                      \
            }                                                                    \
        const float gu = gmin - uj;                                              \
        _Pragma("unroll")                                                        \
        for (int c = 0; c < 4; ++c) w[c] = gu - vv[c];                           \
        bx = nbx; by = nby; bz = nbz;                                            \
        j0 = j1;                                                                 \
    }

// One wave per batch; lane owns columns/rows {lane, 64+lane, 128+lane, 192+lane}.
// JV: column reduction -> greedy claim -> delta-accumulated Dijkstra searches.
// Final form (== R13, session best 1830 us): sentinel used-column exclusion,
// switch fetch, SALU free-test, x2-unrolled expansion loop, 3-DPP/8-readlane
// shallow reduce. Column-min v with u=0 is the empirically best dual init
// (ARR/two-phase/free-argmin all falsified). Ceiling: ~19.5K expansions x
// ~220 cy serial cross-lane chain ~= 1.79 ms — this kernel sits on it.
__launch_bounds__(64, 1)
__global__ void hungarian_wave(const float* __restrict__ pred,
                               const float* __restrict__ target,
                               float* __restrict__ out) {
    const int b    = blockIdx.x;
    const int lane = threadIdx.x;

    const float* pb = pred   + (size_t)b * NPTS * 3;
    const float* tb = target + (size_t)b * NPTS * 3;

    float prx[4], pry[4], prz[4];      // pred (row) points, row = c*64+lane
    float tx[4], ty[4], tz[4];         // target (col) points, col = c*64+lane
    float vv[4], upc[4], Tv[4], w[4], vsave[4];
    float rxc[4], ryc[4], rzc[4];      // matched-row coords, column-attached
    unsigned int kMv[4];               // packed slack keys: (bits(M)&~0xFF)|col
    int   pc[4]  = {-1, -1, -1, -1};   // matched row per column (-1 = free)
    int   way[4];
    unsigned int colu[4];              // this lane's column ids
    unsigned long long freem[4];       // free-COLUMN masks (wave-uniform)

#pragma unroll
    for (int c = 0; c < 4; ++c) {
        int idx = c * 64 + lane;
        prx[c] = pb[idx * 3 + 0]; pry[c] = pb[idx * 3 + 1]; prz[c] = pb[idx * 3 + 2];
        tx[c]  = tb[idx * 3 + 0]; ty[c]  = tb[idx * 3 + 1]; tz[c]  = tb[idx * 3 + 2];
        upc[c] = 0.f; Tv[c] = 0.f; vsave[c] = 0.f;
        rxc[c] = 0.f; ryc[c] = 0.f; rzc[c] = 0.f;
        colu[c] = (unsigned int)idx;
        freem[c] = ~0ull;
    }

    // ---- Phase 1a: column reduction. vv[c] = min_r d(r, col), colrow = argmin ----
    float colmin[4] = {BIGF, BIGF, BIGF, BIGF};
    int   colrow[4] = {0, 0, 0, 0};
#pragma unroll
    for (int rs = 0; rs < 4; ++rs) {
        for (int rl = 0; rl < 64; ++rl) {
            float bx = rlane(prx[rs], rl), by = rlane(pry[rs], rl), bz = rlane(prz[rs], rl);
            int r = rs * 64 + rl;
#pragma unroll
            for (int c = 0; c < 4; ++c) {
                float dx = bx - tx[c], dy = by - ty[c], dz = bz - tz[c];
                float d = rawsqrt(dx * dx + dy * dy + dz * dz);
                if (d < colmin[c]) { colmin[c] = d; colrow[c] = r; }
            }
        }
    }
#pragma unroll
    for (int c = 0; c < 4; ++c) vv[c] = colmin[c];

    // ---- Phase 1b: greedy claim — column (ascending) claims its argmin row if free ----
    unsigned long long frm[4];         // free-row masks (wave-uniform values)
    frm[0] = frm[1] = frm[2] = frm[3] = ~0ull;
#pragma unroll
    for (int cs = 0; cs < 4; ++cs) {
        for (int l = 0; l < 64; ++l) {
            int r = rlanei(colrow[cs], l);
            int rs = r >> 6, rl2 = r & 63;
            unsigned long long bit = 1ull << rl2;
            bool free_row = (SEL4(frm, rs) & bit) != 0ull;
            if (free_row) {
#pragma unroll
                for (int s = 0; s < 4; ++s)
                    if (s == rs) frm[s] &= ~bit;
                float bx, by, bz;
                switch (rs) {
                    case 0:  bx = rlane(prx[0], rl2); by = rlane(pry[0], rl2); bz = rlane(prz[0], rl2); break;
                    case 1:  bx = rlane(prx[1], rl2); by = rlane(pry[1], rl2); bz = rlane(prz[1], rl2); break;
                    case 2:  bx = rlane(prx[2], rl2); by = rlane(pry[2], rl2); bz = rlane(prz[2], rl2); break;
                    default: bx = rlane(prx[3], rl2); by = rlane(pry[3], rl2); bz = rlane(prz[3], rl2); break;
                }
                if (lane == l) {
                    pc[cs] = r; upc[cs] = 0.f;
                    rxc[cs] = bx; ryc[cs] = by; rzc[cs] = bz;
                }
#pragma unroll
                for (int s = 0; s < 4; ++s)
                    if (s == cs) freem[s] &= ~(1ull << l);   // column cs*64+l matched
            }
        }
    }

    // ---- Phase 2: Dijkstra shortest-path for remaining free rows ----
#pragma unroll
    for (int is = 0; is < 4; ++is) {
        unsigned long long m = frm[is];
        while (m) {
            const int il = (int)__builtin_ctzll(m);
            m &= (m - 1);
            const int i = is * 64 + il;

            float rootx, rooty, rootz;
            switch (is) {
                case 0:  rootx = rlane(prx[0], il); rooty = rlane(pry[0], il); rootz = rlane(prz[0], il); break;
                case 1:  rootx = rlane(prx[1], il); rooty = rlane(pry[1], il); rootz = rlane(prz[1], il); break;
                case 2:  rootx = rlane(prx[2], il); rooty = rlane(pry[2], il); rootz = rlane(prz[2], il); break;
                default: rootx = rlane(prx[3], il); rooty = rlane(pry[3], il); rootz = rlane(prz[3], il); break;
            }

#pragma unroll
            for (int c = 0; c < 4; ++c) {
                kMv[c] = KBIG | colu[c];
                w[c]   = -vv[c];
            }
            int usedm = 0;

            float bx = rootx, by = rooty, bz = rootz;
            int j0 = -1;
            int jfin = 0;
            float D = 0.f;

            while (true) {
                EXPAND_ONCE
                EXPAND_ONCE
            }

            // Commit duals for tree columns: net amount = D_final - D_at_use
#pragma unroll
            for (int c = 0; c < 4; ++c)
                if ((usedm >> c) & 1) {
                    vv[c] = vsave[c] + Tv[c] - D;
                    upc[c] += D - Tv[c];
                }

            // Newly matched column leaves the free set
            {
                const int wsl = jfin >> 6;
                const unsigned long long bit = 1ull << (jfin & 63);
#pragma unroll
                for (int s = 0; s < 4; ++s)
                    if (s == wsl) freem[s] &= ~bit;
            }

            // Augment along alternating path (cold)
            int jc = jfin;
            while (true) {
                const int osl = jc >> 6, oln = jc & 63;
                int jw;
                switch (osl) {
                    case 0:  jw = rlanei(way[0], oln); break;
                    case 1:  jw = rlanei(way[1], oln); break;
                    case 2:  jw = rlanei(way[2], oln); break;
                    default: jw = rlanei(way[3], oln); break;
                }
                int np_; float nup, nrx, nry, nrz;
                if (jw < 0) {
                    np_ = i; nup = D; nrx = rootx; nry = rooty; nrz = rootz;
                } else {
                    const int wsl = jw >> 6, wln = jw & 63;
                    switch (wsl) {
                        case 0:  np_ = rlanei(pc[0], wln); nup = rlane(upc[0], wln); nrx = rlane(rxc[0], wln); nry = rlane(ryc[0], wln); nrz = rlane(rzc[0], wln); break;
                        case 1:  np_ = rlanei(pc[1], wln); nup = rlane(upc[1], wln); nrx = rlane(rxc[1], wln); nry = rlane(ryc[1], wln); nrz = rlane(rzc[1], wln); break;
                        case 2:  np_ = rlanei(pc[2], wln); nup = rlane(upc[2], wln); nrx = rlane(rxc[2], wln); nry = rlane(ryc[2], wln); nrz = rlane(rzc[2], wln); break;
                        default: np_ = rlanei(pc[3], wln); nup = rlane(upc[3], wln); nrx = rlane(rxc[3], wln); nry = rlane(ryc[3], wln); nrz = rlane(rzc[3], wln); break;
                    }
                }
#pragma unroll
                for (int c = 0; c < 4; ++c)
                    if (c == osl && lane == oln) {
                        pc[c] = np_; upc[c] = nup;
                        rxc[c] = nrx; ryc[c] = nry; rzc[c] = nrz;
                    }
                if (jw < 0) break;
                jc = jw;
            }
        }
    }

    // ---- Matched cost (coords column-attached; IEEE sqrt for final accuracy) ----
    float s = 0.f;
#pragma unroll
    for (int c = 0; c < 4; ++c) {
        float dx = rxc[c] - tx[c], dy = ryc[c] - ty[c], dz = rzc[c] - tz[c];
        s += sqrtf(dx * dx + dy * dy + dz * dz);
    }
#pragma unroll
    for (int off = 1; off < 64; off <<= 1) s += __shfl_xor(s, off, 64);
    if (lane == 0) atomicAdd(out, s / (float)NBATCH);
}

extern "C" void kernel_launch(void* const* d_in, const int* in_sizes, int n_in,
                              void* d_out, int out_size, void* d_ws, size_t ws_size,
                              hipStream_t stream) {
    const float* pred   = (const float*)d_in[0];
    const float* target = (const float*)d_in[1];
    float* out = (float*)d_out;

    zero_out_kernel<<<1, 64, 0, stream>>>(out, out_size);
    hungarian_wave<<<NBATCH, 64, 0, stream>>>(pred, target, out);
}